// Round 2
// baseline (600.187 us; speedup 1.0000x reference)
//
#include <hip/hip_runtime.h>

// Problem constants (setup_inputs is fixed):
//   b=4, n1=16384, n2=4096  -> N1=65536 fine points, N2=16384 coarse points
//   Cin(x1)=64, Cin(x2)=128, Cout=64
#define N1T 65536
#define N2T 16384
#define NPB1 16384
#define NPB2 4096
#define COUT 64
#define CH 192            // Cout*3 channels, point-major

// ---------------------------------------------------------------------------
// VN linear + leaky-ReLU. One wave handles 8 output channels (wave-uniform ->
// scalar weight loads), lane = position (coalesced x loads). 8 o's per wave
// cuts x re-reads 8x vs 1-o-per-wave and gives a 48:3 fma:load ratio.
// ---------------------------------------------------------------------------
template<int CIN, bool POINT_MAJOR>
__global__ __launch_bounds__(256) void vn_kernel(
    const float* __restrict__ x,   // [CIN][3][N]
    const float* __restrict__ wf,  // [COUT][CIN]
    const float* __restrict__ wd,  // [COUT][CIN]
    float* __restrict__ out,       // POINT_MAJOR ? [N][COUT*3] : [COUT][3][N]
    int N)
{
    const int lane = threadIdx.x & 63;
    const int o0 = __builtin_amdgcn_readfirstlane((blockIdx.x * 4 + (threadIdx.x >> 6)) * 8);
    const int n = blockIdx.y * 64 + lane;

    const float* __restrict__ wfo = wf + o0 * CIN;
    const float* __restrict__ wdo = wd + o0 * CIN;
    const float* __restrict__ xp  = x + n;

    float pa[8][3];
    float da[8][3];
#pragma unroll
    for (int oo = 0; oo < 8; ++oo)
#pragma unroll
        for (int v = 0; v < 3; ++v) { pa[oo][v] = 0.f; da[oo][v] = 0.f; }

    for (int c = 0; c < CIN; ++c) {
        float x0 = xp[(size_t)(c*3+0) * N];
        float x1 = xp[(size_t)(c*3+1) * N];
        float x2 = xp[(size_t)(c*3+2) * N];
#pragma unroll
        for (int oo = 0; oo < 8; ++oo) {
            float wfv = wfo[oo*CIN + c];
            float wdv = wdo[oo*CIN + c];
            pa[oo][0] = fmaf(wfv, x0, pa[oo][0]);
            pa[oo][1] = fmaf(wfv, x1, pa[oo][1]);
            pa[oo][2] = fmaf(wfv, x2, pa[oo][2]);
            da[oo][0] = fmaf(wdv, x0, da[oo][0]);
            da[oo][1] = fmaf(wdv, x1, da[oo][1]);
            da[oo][2] = fmaf(wdv, x2, da[oo][2]);
        }
    }

#pragma unroll
    for (int oo = 0; oo < 8; ++oo) {
        float p0 = pa[oo][0], p1 = pa[oo][1], p2 = pa[oo][2];
        float q0 = da[oo][0], q1 = da[oo][1], q2 = da[oo][2];
        float dot = p0*q0 + p1*q1 + p2*q2;
        float dd  = q0*q0 + q1*q1 + q2*q2;
        float coef = (dot < 0.f) ? (0.8f * dot / (dd + 1e-6f)) : 0.f;
        float r0 = p0 - coef * q0;
        float r1 = p1 - coef * q1;
        float r2 = p2 - coef * q2;
        const int o = o0 + oo;
        if (POINT_MAJOR) {
            float* op = out + (size_t)n * (COUT*3) + o * 3;
            op[0] = r0; op[1] = r1; op[2] = r2;
        } else {
            out[(size_t)(o*3+0) * N + n] = r0;
            out[(size_t)(o*3+1) * N + n] = r1;
            out[(size_t)(o*3+2) * N + n] = r2;
        }
    }
}

// ---------------------------------------------------------------------------
// Brute-force 3-NN, one query per lane. Coarse-point index j is wave-uniform
// -> compiler emits scalar (s_load) broadcasts through the K$; no LDS, no
// shuffle merge. unroll 4 gives independent distance chains for ILP.
// ---------------------------------------------------------------------------
__global__ __launch_bounds__(256) void knn_kernel(
    const float* __restrict__ p1,  // [N1][3]
    const float* __restrict__ p2,  // [N2][3]
    int*   __restrict__ idx_out,   // [3][N1]
    float* __restrict__ w_out)     // [3][N1]
{
    const int fp = blockIdx.x * 256 + threadIdx.x;     // global fine index
    const int bi = fp >> 14;                           // /16384 (uniform per block)
    const float* __restrict__ pc = p2 + (size_t)(bi * NPB2) * 3;

    const float qx = p1[fp*3+0], qy = p1[fp*3+1], qz = p1[fp*3+2];

    float b0 = 1e30f, b1 = 1e30f, b2 = 1e30f;
    int   i0 = 0,     i1 = 0,     i2 = 0;

#pragma unroll 4
    for (int j = 0; j < NPB2; ++j) {
        float dx = qx - pc[j*3+0];
        float dy = qy - pc[j*3+1];
        float dz = qz - pc[j*3+2];
        float d2 = fmaf(dx, dx, fmaf(dy, dy, dz*dz));
        if (d2 < b2) {
            bool l1 = d2 < b1, l0 = d2 < b0;
            float nb1 = l0 ? b0 : (l1 ? d2 : b1);
            int   nj1 = l0 ? i0 : (l1 ? j  : i1);
            b2 = l1 ? b1 : d2;  i2 = l1 ? i1 : j;
            b1 = nb1;           i1 = nj1;
            b0 = l0 ? d2 : b0;  i0 = l0 ? j  : i0;
        }
    }

    float w0 = 1.f / (b0 + 1e-8f);
    float w1 = 1.f / (b1 + 1e-8f);
    float w2 = 1.f / (b2 + 1e-8f);
    float inv = 1.f / (w0 + w1 + w2);
    const int off = bi * NPB2;
    idx_out[0*N1T + fp] = off + i0;
    idx_out[1*N1T + fp] = off + i1;
    idx_out[2*N1T + fp] = off + i2;
    w_out[0*N1T + fp] = w0 * inv;
    w_out[1*N1T + fp] = w1 * inv;
    w_out[2*N1T + fp] = w2 * inv;
}

// ---------------------------------------------------------------------------
// Inverse-distance interpolation + add into out (which already holds y1).
// y2t is point-major [N2][192] so neighbor reads are contiguous 768B rows.
// LDS tile transposes to coalesced [c*3+v][n] output writes.
// ---------------------------------------------------------------------------
__global__ __launch_bounds__(192) void interp_add_kernel(
    const float* __restrict__ y2t,   // [N2][192]
    const int*   __restrict__ idxs,  // [3][N1]
    const float* __restrict__ wts,   // [3][N1]
    float* __restrict__ out)         // [192][N1] += up
{
    __shared__ float tile[64][CH + 1];
    const int base = blockIdx.x * 64;
    const int t = threadIdx.x;       // channel 0..191

    for (int pl = 0; pl < 64; ++pl) {
        const int fp = base + pl;
        const int k0 = idxs[0*N1T + fp];
        const int k1 = idxs[1*N1T + fp];
        const int k2 = idxs[2*N1T + fp];
        const float w0 = wts[0*N1T + fp];
        const float w1 = wts[1*N1T + fp];
        const float w2 = wts[2*N1T + fp];
        float v = w0 * y2t[(size_t)k0 * CH + t]
                + w1 * y2t[(size_t)k1 * CH + t]
                + w2 * y2t[(size_t)k2 * CH + t];
        tile[pl][t] = v;
    }
    __syncthreads();

    const int il = t & 63;
    const int cg = t >> 6;           // 0..2
    for (int ch = cg; ch < CH; ch += 3) {
        const size_t gi = (size_t)ch * N1T + base + il;
        out[gi] += tile[il][ch];
    }
}

// ---------------------------------------------------------------------------
extern "C" void kernel_launch(void* const* d_in, const int* in_sizes, int n_in,
                              void* d_out, int out_size, void* d_ws, size_t ws_size,
                              hipStream_t stream) {
    const float* p1      = (const float*)d_in[0];
    const float* x1      = (const float*)d_in[1];
    const float* p2      = (const float*)d_in[3];
    const float* x2      = (const float*)d_in[4];
    const float* w2_feat = (const float*)d_in[8];
    const float* w2_dir  = (const float*)d_in[9];
    const float* w1_feat = (const float*)d_in[6];
    const float* w1_dir  = (const float*)d_in[7];
    float* out = (float*)d_out;

    // workspace layout
    float* y2t  = (float*)d_ws;                                        // 16384*192*4 = 12.6 MB
    int*   idxs = (int*)((char*)d_ws + (size_t)N2T * CH * 4);          // 3*65536*4
    float* wts  = (float*)((char*)idxs + (size_t)3 * N1T * 4);         // 3*65536*4

    // y2 = VN(x2) -> point-major [N2][192]
    vn_kernel<128, true><<<dim3(2, N2T/64), 256, 0, stream>>>(x2, w2_feat, w2_dir, y2t, N2T);
    // y1 = VN(x1) -> d_out [64][3][N1]
    vn_kernel<64, false><<<dim3(2, N1T/64), 256, 0, stream>>>(x1, w1_feat, w1_dir, out, N1T);
    // 3-NN (independent of the above)
    knn_kernel<<<dim3(N1T/256), 256, 0, stream>>>(p1, p2, idxs, wts);
    // out += interpolate(y2)
    interp_add_kernel<<<dim3(N1T/64), 192, 0, stream>>>(y2t, idxs, wts, out);
}

// Round 3
// 291.537 us; speedup vs baseline: 2.0587x; 2.0587x over previous
//
#include <hip/hip_runtime.h>

// Problem constants (setup_inputs is fixed):
//   b=4, n1=16384, n2=4096  -> N1=65536 fine points, N2=16384 coarse points
//   Cin(x1)=64, Cin(x2)=128, Cout=64
#define N1T 65536
#define N2T 16384
#define NPB2 4096
#define COUT 64
#define CH 192            // Cout*3 channels, point-major

// ---------------------------------------------------------------------------
// VN linear + leaky-ReLU. One block = one 64-point tile; x chunk staged in
// LDS once (48KB), so x is read OBLK/64 times total instead of 8x. Each wave
// owns OBLK/4 output channels (wave-uniform -> scalar weight loads).
// ---------------------------------------------------------------------------
template<int CIN, int OBLK, bool POINT_MAJOR>
__global__ __launch_bounds__(256) void vn_kernel(
    const float* __restrict__ x,   // [CIN][3][N]
    const float* __restrict__ wf,  // [COUT][CIN]
    const float* __restrict__ wd,  // [COUT][CIN]
    float* __restrict__ out,       // POINT_MAJOR ? [N][COUT*3] : [COUT][3][N]
    int N)
{
    constexpr int OPW = OBLK / 4;            // o's per wave
    __shared__ float xs[192][64];            // 64 cin x 3 comps x 64 pts = 48KB

    const int lane = threadIdx.x & 63;
    const int wave = threadIdx.x >> 6;
    const int n0   = blockIdx.y * 64;
    const int n    = n0 + lane;
    const int o0   = __builtin_amdgcn_readfirstlane(blockIdx.x * OBLK + wave * OPW);

    float pa[OPW][3], da[OPW][3];
#pragma unroll
    for (int oo = 0; oo < OPW; ++oo)
#pragma unroll
        for (int v = 0; v < 3; ++v) { pa[oo][v] = 0.f; da[oo][v] = 0.f; }

    for (int cc = 0; cc < CIN; cc += 64) {
        if (cc) __syncthreads();
        // stage rows [cc*3, cc*3+192) x 64 pts, coalesced (1 row per wave-pass)
        for (int i = threadIdx.x; i < 192 * 64; i += 256) {
            const int row = i >> 6, pt = i & 63;
            xs[row][pt] = x[(size_t)(cc * 3 + row) * N + n0 + pt];
        }
        __syncthreads();

#pragma unroll 4
        for (int c = 0; c < 64; ++c) {
            const float x0 = xs[c*3+0][lane];
            const float x1 = xs[c*3+1][lane];
            const float x2 = xs[c*3+2][lane];
#pragma unroll
            for (int oo = 0; oo < OPW; ++oo) {
                const float wfv = wf[(size_t)(o0 + oo) * CIN + cc + c];
                const float wdv = wd[(size_t)(o0 + oo) * CIN + cc + c];
                pa[oo][0] = fmaf(wfv, x0, pa[oo][0]);
                pa[oo][1] = fmaf(wfv, x1, pa[oo][1]);
                pa[oo][2] = fmaf(wfv, x2, pa[oo][2]);
                da[oo][0] = fmaf(wdv, x0, da[oo][0]);
                da[oo][1] = fmaf(wdv, x1, da[oo][1]);
                da[oo][2] = fmaf(wdv, x2, da[oo][2]);
            }
        }
    }

#pragma unroll
    for (int oo = 0; oo < OPW; ++oo) {
        float p0 = pa[oo][0], p1 = pa[oo][1], p2 = pa[oo][2];
        float q0 = da[oo][0], q1 = da[oo][1], q2 = da[oo][2];
        float dot = p0*q0 + p1*q1 + p2*q2;
        float dd  = q0*q0 + q1*q1 + q2*q2;
        float coef = (dot < 0.f) ? (0.8f * dot / (dd + 1e-6f)) : 0.f;
        float r0 = p0 - coef * q0;
        float r1 = p1 - coef * q1;
        float r2 = p2 - coef * q2;
        const int o = o0 + oo;
        if (POINT_MAJOR) {
            float* op = out + (size_t)n * (COUT*3) + o * 3;
            op[0] = r0; op[1] = r1; op[2] = r2;
        } else {
            out[(size_t)(o*3+0) * N + n] = r0;
            out[(size_t)(o*3+1) * N + n] = r1;
            out[(size_t)(o*3+2) * N + n] = r2;
        }
    }
}

// ---------------------------------------------------------------------------
// Brute-force 3-NN. 16 queries/wave x 4 sub-lanes each scanning an
// interleaved quarter of the 4096 staged coarse points. BRANCHLESS
// full-precision top-3 insert (3 v_cmp + 10 v_cndmask) -- no exec-mask
// churn, VALU-throughput-bound by design.
// ---------------------------------------------------------------------------
#define KNN_INSERT(d2, j)                                        \
    {                                                            \
        const bool c0 = (d2) < b0;                               \
        const bool c1 = (d2) < b1;                               \
        const bool c2 = (d2) < b2;                               \
        const float nb2 = c2 ? (c1 ? b1 : (d2)) : b2;            \
        const int   ni2 = c2 ? (c1 ? i1 : (j))  : i2;            \
        const float nb1 = c1 ? (c0 ? b0 : (d2)) : b1;            \
        const int   ni1 = c1 ? (c0 ? i0 : (j))  : i1;            \
        b0 = c0 ? (d2) : b0;  i0 = c0 ? (j) : i0;                \
        b1 = nb1; i1 = ni1; b2 = nb2; i2 = ni2;                  \
    }

__global__ __launch_bounds__(256) void knn_kernel(
    const float* __restrict__ p1,  // [N1][3]
    const float* __restrict__ p2,  // [N2][3]
    int*   __restrict__ idx_out,   // [3][N1]
    float* __restrict__ w_out)     // [3][N1]
{
    __shared__ float sx[NPB2], sy[NPB2], sz[NPB2];
    const int bi = blockIdx.x >> 8;            // 256 blocks per batch
    const float* __restrict__ pc = p2 + (size_t)bi * NPB2 * 3;
    // coalesced flat staging (i/3, i%3 via compiler magic-div)
    for (int i = threadIdx.x; i < NPB2 * 3; i += 256) {
        const float v = pc[i];
        const int j = i / 3, r = i - j * 3;
        if (r == 0) sx[j] = v; else if (r == 1) sy[j] = v; else sz[j] = v;
    }
    __syncthreads();

    const int t  = threadIdx.x;
    const int q  = t & 3;
    const int fp = blockIdx.x * 64 + (t >> 2);   // global fine index
    const float qx = p1[fp*3+0], qy = p1[fp*3+1], qz = p1[fp*3+2];

    float b0 = 1e30f, b1 = 1e30f, b2 = 1e30f;
    int   i0 = 0,     i1 = 0,     i2 = 0;

#pragma unroll 4
    for (int jj = 0; jj < NPB2 / 4; ++jj) {
        const int j = q + (jj << 2);
        const float dx = qx - sx[j];
        const float dy = qy - sy[j];
        const float dz = qz - sz[j];
        const float d2 = fmaf(dx, dx, fmaf(dy, dy, dz * dz));
        KNN_INSERT(d2, j)
    }

    // merge the 4 sub-lane top-3 lists (lanes grouped by fine point)
#pragma unroll
    for (int m = 1; m <= 2; m <<= 1) {
        const float c0v = __shfl_xor(b0, m, 4);
        const float c1v = __shfl_xor(b1, m, 4);
        const float c2v = __shfl_xor(b2, m, 4);
        const int   j0v = __shfl_xor(i0, m, 4);
        const int   j1v = __shfl_xor(i1, m, 4);
        const int   j2v = __shfl_xor(i2, m, 4);
        KNN_INSERT(c0v, j0v)
        KNN_INSERT(c1v, j1v)
        KNN_INSERT(c2v, j2v)
    }

    if (q == 0) {
        const float w0 = 1.f / (b0 + 1e-8f);
        const float w1 = 1.f / (b1 + 1e-8f);
        const float w2 = 1.f / (b2 + 1e-8f);
        const float inv = 1.f / (w0 + w1 + w2);
        const int off = bi * NPB2;
        idx_out[0*N1T + fp] = off + i0;
        idx_out[1*N1T + fp] = off + i1;
        idx_out[2*N1T + fp] = off + i2;
        w_out[0*N1T + fp] = w0 * inv;
        w_out[1*N1T + fp] = w1 * inv;
        w_out[2*N1T + fp] = w2 * inv;
    }
}

// ---------------------------------------------------------------------------
// Inverse-distance interpolation + add into out (which already holds y1).
// y2t is point-major [N2][192] so neighbor reads are contiguous 768B rows
// (L2-resident); idx/wts loads are wave-uniform -> scalar. LDS tile
// transposes to coalesced [c*3+v][n] output writes.
// ---------------------------------------------------------------------------
__global__ __launch_bounds__(192) void interp_add_kernel(
    const float* __restrict__ y2t,   // [N2][192]
    const int*   __restrict__ idxs,  // [3][N1]
    const float* __restrict__ wts,   // [3][N1]
    float* __restrict__ out)         // [192][N1] += up
{
    __shared__ float tile[64][CH + 1];
    const int base = blockIdx.x * 64;
    const int t = threadIdx.x;       // channel 0..191

    for (int pl = 0; pl < 64; ++pl) {
        const int fp = base + pl;
        const int k0 = idxs[0*N1T + fp];
        const int k1 = idxs[1*N1T + fp];
        const int k2 = idxs[2*N1T + fp];
        const float w0 = wts[0*N1T + fp];
        const float w1 = wts[1*N1T + fp];
        const float w2 = wts[2*N1T + fp];
        float v = w0 * y2t[(size_t)k0 * CH + t]
                + w1 * y2t[(size_t)k1 * CH + t]
                + w2 * y2t[(size_t)k2 * CH + t];
        tile[pl][t] = v;
    }
    __syncthreads();

    const int il = t & 63;
    const int cg = t >> 6;           // 0..2
    for (int ch = cg; ch < CH; ch += 3) {
        const size_t gi = (size_t)ch * N1T + base + il;
        out[gi] += tile[il][ch];
    }
}

// ---------------------------------------------------------------------------
extern "C" void kernel_launch(void* const* d_in, const int* in_sizes, int n_in,
                              void* d_out, int out_size, void* d_ws, size_t ws_size,
                              hipStream_t stream) {
    const float* p1      = (const float*)d_in[0];
    const float* x1      = (const float*)d_in[1];
    const float* p2      = (const float*)d_in[3];
    const float* x2      = (const float*)d_in[4];
    const float* w1_feat = (const float*)d_in[6];
    const float* w1_dir  = (const float*)d_in[7];
    const float* w2_feat = (const float*)d_in[8];
    const float* w2_dir  = (const float*)d_in[9];
    float* out = (float*)d_out;

    // workspace layout
    float* y2t  = (float*)d_ws;                                        // 16384*192*4 = 12.6 MB
    int*   idxs = (int*)((char*)d_ws + (size_t)N2T * CH * 4);          // 3*65536*4
    float* wts  = (float*)((char*)idxs + (size_t)3 * N1T * 4);         // 3*65536*4

    // 3-NN (independent)
    knn_kernel<<<dim3(N1T/64), 256, 0, stream>>>(p1, p2, idxs, wts);
    // y2 = VN(x2) -> point-major [N2][192]; 32 o's/block (2 blocks per tile)
    vn_kernel<128, 32, true><<<dim3(2, N2T/64), 256, 0, stream>>>(x2, w2_feat, w2_dir, y2t, N2T);
    // y1 = VN(x1) -> d_out [64][3][N1]; all 64 o's/block
    vn_kernel<64, 64, false><<<dim3(1, N1T/64), 256, 0, stream>>>(x1, w1_feat, w1_dir, out, N1T);
    // out += interpolate(y2)
    interp_add_kernel<<<dim3(N1T/64), 192, 0, stream>>>(y2t, idxs, wts, out);
}

// Round 4
// 217.376 us; speedup vs baseline: 2.7611x; 1.3412x over previous
//
#include <hip/hip_runtime.h>

// Problem constants (setup_inputs is fixed):
//   b=4, n1=16384, n2=4096  -> N1=65536 fine points, N2=16384 coarse points
//   Cin(x1)=64, Cin(x2)=128, Cout=64
#define N1T 65536
#define N2T 16384
#define NPB2 4096
#define COUT 64
#define CH 192            // Cout*3 channels, point-major
#define GRD 8             // knn grid resolution per dim
#define NCELL 512         // 8^3 cells per batch
#define HCELL 0.125f

// ---------------------------------------------------------------------------
// VN linear + leaky-ReLU. One block = one 64-point tile; x chunk staged in
// LDS once (48KB). Each wave owns OBLK/4 output channels (wave-uniform ->
// scalar weight loads).
// ---------------------------------------------------------------------------
template<int CIN, int OBLK, bool POINT_MAJOR>
__global__ __launch_bounds__(256) void vn_kernel(
    const float* __restrict__ x,   // [CIN][3][N]
    const float* __restrict__ wf,  // [COUT][CIN]
    const float* __restrict__ wd,  // [COUT][CIN]
    float* __restrict__ out,       // POINT_MAJOR ? [N][COUT*3] : [COUT][3][N]
    int N)
{
    constexpr int OPW = OBLK / 4;            // o's per wave
    __shared__ float xs[192][64];            // 64 cin x 3 comps x 64 pts = 48KB

    const int lane = threadIdx.x & 63;
    const int wave = threadIdx.x >> 6;
    const int n0   = blockIdx.y * 64;
    const int n    = n0 + lane;
    const int o0   = __builtin_amdgcn_readfirstlane(blockIdx.x * OBLK + wave * OPW);

    float pa[OPW][3], da[OPW][3];
#pragma unroll
    for (int oo = 0; oo < OPW; ++oo)
#pragma unroll
        for (int v = 0; v < 3; ++v) { pa[oo][v] = 0.f; da[oo][v] = 0.f; }

    for (int cc = 0; cc < CIN; cc += 64) {
        if (cc) __syncthreads();
        for (int i = threadIdx.x; i < 192 * 64; i += 256) {
            const int row = i >> 6, pt = i & 63;
            xs[row][pt] = x[(size_t)(cc * 3 + row) * N + n0 + pt];
        }
        __syncthreads();

#pragma unroll 4
        for (int c = 0; c < 64; ++c) {
            const float x0 = xs[c*3+0][lane];
            const float x1 = xs[c*3+1][lane];
            const float x2 = xs[c*3+2][lane];
#pragma unroll
            for (int oo = 0; oo < OPW; ++oo) {
                const float wfv = wf[(size_t)(o0 + oo) * CIN + cc + c];
                const float wdv = wd[(size_t)(o0 + oo) * CIN + cc + c];
                pa[oo][0] = fmaf(wfv, x0, pa[oo][0]);
                pa[oo][1] = fmaf(wfv, x1, pa[oo][1]);
                pa[oo][2] = fmaf(wfv, x2, pa[oo][2]);
                da[oo][0] = fmaf(wdv, x0, da[oo][0]);
                da[oo][1] = fmaf(wdv, x1, da[oo][1]);
                da[oo][2] = fmaf(wdv, x2, da[oo][2]);
            }
        }
    }

#pragma unroll
    for (int oo = 0; oo < OPW; ++oo) {
        float p0 = pa[oo][0], p1 = pa[oo][1], p2 = pa[oo][2];
        float q0 = da[oo][0], q1 = da[oo][1], q2 = da[oo][2];
        float dot = p0*q0 + p1*q1 + p2*q2;
        float dd  = q0*q0 + q1*q1 + q2*q2;
        float coef = (dot < 0.f) ? (0.8f * dot / (dd + 1e-6f)) : 0.f;
        float r0 = p0 - coef * q0;
        float r1 = p1 - coef * q1;
        float r2 = p2 - coef * q2;
        const int o = o0 + oo;
        if (POINT_MAJOR) {
            float* op = out + (size_t)n * (COUT*3) + o * 3;
            op[0] = r0; op[1] = r1; op[2] = r2;
        } else {
            out[(size_t)(o*3+0) * N + n] = r0;
            out[(size_t)(o*3+1) * N + n] = r1;
            out[(size_t)(o*3+2) * N + n] = r2;
        }
    }
}

// ---------------------------------------------------------------------------
// kNN via uniform-grid binning. Branchless full-precision top-3 insert.
// ---------------------------------------------------------------------------
#define KNN_INSERT(d2, j)                                        \
    {                                                            \
        const bool c0 = (d2) < b0;                               \
        const bool c1 = (d2) < b1;                               \
        const bool c2 = (d2) < b2v;                              \
        const float nb2 = c2 ? (c1 ? b1 : (d2)) : b2v;           \
        const int   ni2 = c2 ? (c1 ? i1 : (j))  : i2;            \
        const float nb1 = c1 ? (c0 ? b0 : (d2)) : b1;            \
        const int   ni1 = c1 ? (c0 ? i0 : (j))  : i1;            \
        b0 = c0 ? (d2) : b0;  i0 = c0 ? (j) : i0;                \
        b1 = nb1; i1 = ni1; b2v = nb2; i2 = ni2;                 \
    }

__global__ __launch_bounds__(256) void zero_kernel(int* __restrict__ p, int n) {
    const int i = blockIdx.x * 256 + threadIdx.x;
    if (i < n) p[i] = 0;
}

__device__ __forceinline__ int cell_of(float x, float y, float z) {
    int cx = (int)(x * (float)GRD); cx = cx < 0 ? 0 : (cx > GRD-1 ? GRD-1 : cx);
    int cy = (int)(y * (float)GRD); cy = cy < 0 ? 0 : (cy > GRD-1 ? GRD-1 : cy);
    int cz = (int)(z * (float)GRD); cz = cz < 0 ? 0 : (cz > GRD-1 ? GRD-1 : cz);
    return (cz << 6) | (cy << 3) | cx;
}

__global__ __launch_bounds__(256) void bin_count_kernel(
    const float* __restrict__ p2, int* __restrict__ counts) {
    const int i = blockIdx.x * 256 + threadIdx.x;      // 0..16383
    const float x = p2[i*3+0], y = p2[i*3+1], z = p2[i*3+2];
    const int cell = ((i >> 12) << 9) | cell_of(x, y, z);
    atomicAdd(&counts[cell], 1);
}

// exclusive scan of counts[2048] -> off[0..2048]
__global__ __launch_bounds__(256) void scan_kernel(
    const int* __restrict__ counts, int* __restrict__ off) {
    __shared__ int buf[2][256];
    const int t = threadIdx.x;
    int v[8]; int s = 0;
#pragma unroll
    for (int j = 0; j < 8; ++j) { const int tmp = counts[t*8+j]; v[j] = s; s += tmp; }
    buf[0][t] = s; __syncthreads();
    int src = 0;
    for (int d = 1; d < 256; d <<= 1) {
        int val = buf[src][t];
        if (t >= d) val += buf[src][t - d];
        buf[src ^ 1][t] = val; src ^= 1; __syncthreads();
    }
    const int incl = buf[src][t];
    const int base = incl - s;
#pragma unroll
    for (int j = 0; j < 8; ++j) off[t*8+j] = base + v[j];
    if (t == 255) off[2048] = incl;
}

__global__ __launch_bounds__(256) void bin_scatter_kernel(
    const float* __restrict__ p2, const int* __restrict__ off,
    int* __restrict__ cnt2, float4* __restrict__ binned) {
    const int i = blockIdx.x * 256 + threadIdx.x;      // 0..16383
    const float x = p2[i*3+0], y = p2[i*3+1], z = p2[i*3+2];
    const int cell = ((i >> 12) << 9) | cell_of(x, y, z);
    const int pos = off[cell] + atomicAdd(&cnt2[cell], 1);
    binned[pos] = make_float4(x, y, z, __int_as_float(i));
}

// 2 lanes per query; each scans half of every neighbor cell's point range,
// then one shfl-xor merge. Exact: accept only if 3rd-best dist is closer
// than any unscanned region; else masked brute-force rescan (rare).
__global__ __launch_bounds__(256) void knn_grid_kernel(
    const float* __restrict__ p1,      // [N1][3]
    const float4* __restrict__ binned, // [N2] (x,y,z,idx)
    const int* __restrict__ off,       // [2049]
    int*   __restrict__ idx_out,       // [3][N1]
    float* __restrict__ w_out)         // [3][N1]
{
    const int t   = blockIdx.x * 256 + threadIdx.x;
    const int fp  = t >> 1;
    const int sub = t & 1;
    const int bi  = fp >> 14;
    const int cbase = bi << 9;

    const float qx = p1[fp*3+0], qy = p1[fp*3+1], qz = p1[fp*3+2];
    int cx = (int)(qx * (float)GRD); cx = cx < 0 ? 0 : (cx > 7 ? 7 : cx);
    int cy = (int)(qy * (float)GRD); cy = cy < 0 ? 0 : (cy > 7 ? 7 : cy);
    int cz = (int)(qz * (float)GRD); cz = cz < 0 ? 0 : (cz > 7 ? 7 : cz);

    float b0 = 1e30f, b1 = 1e30f, b2v = 1e30f;
    int   i0 = 0,     i1 = 0,     i2 = 0;

    for (int dz = -1; dz <= 1; ++dz)
    for (int dy = -1; dy <= 1; ++dy)
    for (int dx = -1; dx <= 1; ++dx) {
        const int nx = cx + dx, ny = cy + dy, nz = cz + dz;
        if ((unsigned)nx > 7u || (unsigned)ny > 7u || (unsigned)nz > 7u) continue;
        const int c = cbase + (nz << 6) + (ny << 3) + nx;
        const int s = off[c], e = off[c + 1];
        for (int k = s + sub; k < e; k += 2) {
            const float4 c4 = binned[k];
            const float ddx = qx - c4.x, ddy = qy - c4.y, ddz = qz - c4.z;
            const float d2 = fmaf(ddx, ddx, fmaf(ddy, ddy, ddz * ddz));
            const int j = __float_as_int(c4.w);
            KNN_INSERT(d2, j)
        }
    }

    // merge the pair
    {
        const float c0v = __shfl_xor(b0, 1, 2);
        const float c1v = __shfl_xor(b1, 1, 2);
        const float c2v = __shfl_xor(b2v, 1, 2);
        const int   j0v = __shfl_xor(i0, 1, 2);
        const int   j1v = __shfl_xor(i1, 1, 2);
        const int   j2v = __shfl_xor(i2, 1, 2);
        KNN_INSERT(c0v, j0v)
        KNN_INSERT(c1v, j1v)
        KNN_INSERT(c2v, j2v)
    }

    // exactness check: nearest unscanned region (walls beyond [0,1] excluded)
    float dw = 1e30f;
    if (cx >= 2) dw = fminf(dw, qx - (float)(cx - 1) * HCELL);
    if (cx <= 5) dw = fminf(dw, (float)(cx + 2) * HCELL - qx);
    if (cy >= 2) dw = fminf(dw, qy - (float)(cy - 1) * HCELL);
    if (cy <= 5) dw = fminf(dw, (float)(cy + 2) * HCELL - qy);
    if (cz >= 2) dw = fminf(dw, qz - (float)(cz - 1) * HCELL);
    if (cz <= 5) dw = fminf(dw, (float)(cz + 2) * HCELL - qz);
    const bool done = b2v < dw * dw;

    if (!done) {   // rare; pair-uniform predicate
        b0 = b1 = b2v = 1e30f; i0 = i1 = i2 = 0;
        const int s = bi << 12, e = (bi + 1) << 12;
        for (int k = s + sub; k < e; k += 2) {
            const float4 c4 = binned[k];
            const float ddx = qx - c4.x, ddy = qy - c4.y, ddz = qz - c4.z;
            const float d2 = fmaf(ddx, ddx, fmaf(ddy, ddy, ddz * ddz));
            const int j = __float_as_int(c4.w);
            KNN_INSERT(d2, j)
        }
        const float c0v = __shfl_xor(b0, 1, 2);
        const float c1v = __shfl_xor(b1, 1, 2);
        const float c2v = __shfl_xor(b2v, 1, 2);
        const int   j0v = __shfl_xor(i0, 1, 2);
        const int   j1v = __shfl_xor(i1, 1, 2);
        const int   j2v = __shfl_xor(i2, 1, 2);
        KNN_INSERT(c0v, j0v)
        KNN_INSERT(c1v, j1v)
        KNN_INSERT(c2v, j2v)
    }

    if (sub == 0) {
        const float w0 = 1.f / (b0 + 1e-8f);
        const float w1 = 1.f / (b1 + 1e-8f);
        const float w2 = 1.f / (b2v + 1e-8f);
        const float inv = 1.f / (w0 + w1 + w2);
        idx_out[0*N1T + fp] = i0;
        idx_out[1*N1T + fp] = i1;
        idx_out[2*N1T + fp] = i2;
        w_out[0*N1T + fp] = w0 * inv;
        w_out[1*N1T + fp] = w1 * inv;
        w_out[2*N1T + fp] = w2 * inv;
    }
}

// ---------------------------------------------------------------------------
// Inverse-distance interpolation + add into out (which already holds y1).
// ---------------------------------------------------------------------------
__global__ __launch_bounds__(192) void interp_add_kernel(
    const float* __restrict__ y2t,   // [N2][192]
    const int*   __restrict__ idxs,  // [3][N1]
    const float* __restrict__ wts,   // [3][N1]
    float* __restrict__ out)         // [192][N1] += up
{
    __shared__ float tile[64][CH + 1];
    const int base = blockIdx.x * 64;
    const int t = threadIdx.x;       // channel 0..191

    for (int pl = 0; pl < 64; ++pl) {
        const int fp = base + pl;
        const int k0 = idxs[0*N1T + fp];
        const int k1 = idxs[1*N1T + fp];
        const int k2 = idxs[2*N1T + fp];
        const float w0 = wts[0*N1T + fp];
        const float w1 = wts[1*N1T + fp];
        const float w2 = wts[2*N1T + fp];
        float v = w0 * y2t[(size_t)k0 * CH + t]
                + w1 * y2t[(size_t)k1 * CH + t]
                + w2 * y2t[(size_t)k2 * CH + t];
        tile[pl][t] = v;
    }
    __syncthreads();

    const int il = t & 63;
    const int cg = t >> 6;           // 0..2
    for (int ch = cg; ch < CH; ch += 3) {
        const size_t gi = (size_t)ch * N1T + base + il;
        out[gi] += tile[il][ch];
    }
}

// ---------------------------------------------------------------------------
extern "C" void kernel_launch(void* const* d_in, const int* in_sizes, int n_in,
                              void* d_out, int out_size, void* d_ws, size_t ws_size,
                              hipStream_t stream) {
    const float* p1      = (const float*)d_in[0];
    const float* x1      = (const float*)d_in[1];
    const float* p2      = (const float*)d_in[3];
    const float* x2      = (const float*)d_in[4];
    const float* w1_feat = (const float*)d_in[6];
    const float* w1_dir  = (const float*)d_in[7];
    const float* w2_feat = (const float*)d_in[8];
    const float* w2_dir  = (const float*)d_in[9];
    float* out = (float*)d_out;

    // workspace layout (all chunks 16B-aligned)
    char* ws = (char*)d_ws;
    float*  y2t    = (float*)ws;                 ws += (size_t)N2T * CH * 4;   // 12.58 MB
    int*    idxs   = (int*)ws;                   ws += (size_t)3 * N1T * 4;    // 0.75 MB
    float*  wts    = (float*)ws;                 ws += (size_t)3 * N1T * 4;    // 0.75 MB
    int*    counts = (int*)ws;                   ws += 2048 * 4;
    int*    cnt2   = (int*)ws;                   ws += 2048 * 4;
    int*    off    = (int*)ws;                   ws += 2064 * 4;               // 2049 used
    float4* binned = (float4*)ws;                                              // 16384*16B

    // ---- kNN chain ----
    zero_kernel<<<16, 256, 0, stream>>>(counts, 4096);        // counts + cnt2 (contiguous)
    bin_count_kernel<<<N2T/256, 256, 0, stream>>>(p2, counts);
    scan_kernel<<<1, 256, 0, stream>>>(counts, off);
    bin_scatter_kernel<<<N2T/256, 256, 0, stream>>>(p2, off, cnt2, binned);
    knn_grid_kernel<<<(2*N1T)/256, 256, 0, stream>>>(p1, binned, off, idxs, wts);

    // y2 = VN(x2) -> point-major [N2][192]; 32 o's/block
    vn_kernel<128, 32, true><<<dim3(2, N2T/64), 256, 0, stream>>>(x2, w2_feat, w2_dir, y2t, N2T);
    // y1 = VN(x1) -> d_out [64][3][N1]; all 64 o's/block
    vn_kernel<64, 64, false><<<dim3(1, N1T/64), 256, 0, stream>>>(x1, w1_feat, w1_dir, out, N1T);
    // out += interpolate(y2)
    interp_add_kernel<<<dim3(N1T/64), 192, 0, stream>>>(y2t, idxs, wts, out);
}

// Round 5
// 156.692 us; speedup vs baseline: 3.8304x; 1.3873x over previous
//
#include <hip/hip_runtime.h>

// Problem constants (setup_inputs is fixed):
//   b=4, n1=16384, n2=4096  -> N1=65536 fine points, N2=16384 coarse points
//   Cin(x1)=64, Cin(x2)=128, Cout=64
#define N1T 65536
#define N2T 16384
#define COUT 64
#define CH 192            // Cout*3 channels, point-major
#define GRD 8             // knn grid resolution per dim
#define HCELL 0.125f

// ---------------------------------------------------------------------------
// VN linear + leaky-ReLU (+ optional fused interpolation-add epilogue).
// 512 threads = 8 waves; each wave owns 8 output channels (48 accumulator
// VGPRs), lane = point. x chunk staged once in LDS (48KB), so x global
// traffic is 1x. FUSE: result -> LDS tile [64][193], add 3-NN inverse-dist
// gather from y2t (coalesced 768B rows), transpose-write out once.
// ---------------------------------------------------------------------------
template<int CIN, bool FUSE>
__global__ __launch_bounds__(512, 6) void vn_kernel(
    const float* __restrict__ x,    // [CIN][3][N]
    const float* __restrict__ wf,   // [COUT][CIN]
    const float* __restrict__ wd,   // [COUT][CIN]
    const int*   __restrict__ idxs, // [3][N1] (FUSE only)
    const float* __restrict__ wts,  // [3][N1] (FUSE only)
    const float* __restrict__ y2t,  // [N2][192] (FUSE only)
    float* __restrict__ out,        // FUSE ? [192][N1] : [N][192] point-major
    int N)
{
    __shared__ float buf[12352];    // xs[192][64] overlay / tile[64][193]
    __shared__ int   sk[3][64];
    __shared__ float sw[3][64];

    const int tid  = threadIdx.x;
    const int lane = tid & 63;
    const int wave = tid >> 6;                  // 0..7
    const int n0   = blockIdx.x * 64;
    const int o0   = __builtin_amdgcn_readfirstlane(wave * 8);

    float pa[8][3], da[8][3];
#pragma unroll
    for (int oo = 0; oo < 8; ++oo)
#pragma unroll
        for (int v = 0; v < 3; ++v) { pa[oo][v] = 0.f; da[oo][v] = 0.f; }

    for (int cc = 0; cc < CIN; cc += 64) {
        if (cc) __syncthreads();
        // stage 192 rows x 64 pts, float4 (16 float4 per row)
#pragma unroll
        for (int k = 0; k < 6; ++k) {
            const int i4  = k * 512 + tid;      // 0..3071
            const int row = i4 >> 4, p4 = i4 & 15;
            const float4 v = *(const float4*)&x[(size_t)(cc * 3 + row) * N + n0 + p4 * 4];
            *(float4*)&buf[row * 64 + p4 * 4] = v;
        }
        if (FUSE && cc == 0 && tid < 192) {
            const int r = tid >> 6, pt = tid & 63;
            sk[r][pt] = idxs[r * N1T + n0 + pt];
            sw[r][pt] = wts[r * N1T + n0 + pt];
        }
        __syncthreads();

#pragma unroll 2
        for (int c = 0; c < 64; ++c) {
            const float x0 = buf[(c*3+0)*64 + lane];
            const float x1 = buf[(c*3+1)*64 + lane];
            const float x2 = buf[(c*3+2)*64 + lane];
#pragma unroll
            for (int oo = 0; oo < 8; ++oo) {
                const float wfv = wf[(size_t)(o0 + oo) * CIN + cc + c];
                const float wdv = wd[(size_t)(o0 + oo) * CIN + cc + c];
                pa[oo][0] = fmaf(wfv, x0, pa[oo][0]);
                pa[oo][1] = fmaf(wfv, x1, pa[oo][1]);
                pa[oo][2] = fmaf(wfv, x2, pa[oo][2]);
                da[oo][0] = fmaf(wdv, x0, da[oo][0]);
                da[oo][1] = fmaf(wdv, x1, da[oo][1]);
                da[oo][2] = fmaf(wdv, x2, da[oo][2]);
            }
        }
    }

    float r[8][3];
#pragma unroll
    for (int oo = 0; oo < 8; ++oo) {
        const float p0 = pa[oo][0], p1 = pa[oo][1], p2 = pa[oo][2];
        const float q0 = da[oo][0], q1 = da[oo][1], q2 = da[oo][2];
        const float dot = p0*q0 + p1*q1 + p2*q2;
        const float dd  = q0*q0 + q1*q1 + q2*q2;
        const float coef = (dot < 0.f) ? (0.8f * dot / (dd + 1e-6f)) : 0.f;
        r[oo][0] = p0 - coef * q0;
        r[oo][1] = p1 - coef * q1;
        r[oo][2] = p2 - coef * q2;
    }

    if (!FUSE) {
        // point-major [n][o*3+v]
        float* op = out + (size_t)(n0 + lane) * CH + o0 * 3;
#pragma unroll
        for (int oo = 0; oo < 8; ++oo) {
            op[oo*3+0] = r[oo][0];
            op[oo*3+1] = r[oo][1];
            op[oo*3+2] = r[oo][2];
        }
    } else {
        __syncthreads();                         // done reading xs
#pragma unroll
        for (int oo = 0; oo < 8; ++oo) {
            buf[lane * 193 + (o0 + oo) * 3 + 0] = r[oo][0];
            buf[lane * 193 + (o0 + oo) * 3 + 1] = r[oo][1];
            buf[lane * 193 + (o0 + oo) * 3 + 2] = r[oo][2];
        }
        __syncthreads();
        // phase A: += inverse-distance gather (768B-contiguous y2t rows)
        for (int k = 0; k < 24; ++k) {
            const int e  = k * 512 + tid;        // 0..12287
            const int pt = e / CH, ch = e - pt * CH;
            const float up = sw[0][pt] * y2t[(size_t)sk[0][pt] * CH + ch]
                           + sw[1][pt] * y2t[(size_t)sk[1][pt] * CH + ch]
                           + sw[2][pt] * y2t[(size_t)sk[2][pt] * CH + ch];
            buf[pt * 193 + ch] += up;
        }
        __syncthreads();
        // phase B: coalesced transpose-write of the final output
#pragma unroll
        for (int rr = 0; rr < 24; ++rr) {
            const int ch = wave + (rr << 3);
            out[(size_t)ch * N1T + n0 + lane] = buf[lane * 193 + ch];
        }
    }
}

// ---------------------------------------------------------------------------
// kNN via uniform-grid binning. Branchless full-precision top-3 insert.
// ---------------------------------------------------------------------------
#define KNN_INSERT(d2, j)                                        \
    {                                                            \
        const bool c0 = (d2) < b0;                               \
        const bool c1 = (d2) < b1;                               \
        const bool c2 = (d2) < b2v;                              \
        const float nb2 = c2 ? (c1 ? b1 : (d2)) : b2v;           \
        const int   ni2 = c2 ? (c1 ? i1 : (j))  : i2;            \
        const float nb1 = c1 ? (c0 ? b0 : (d2)) : b1;            \
        const int   ni1 = c1 ? (c0 ? i0 : (j))  : i1;            \
        b0 = c0 ? (d2) : b0;  i0 = c0 ? (j) : i0;                \
        b1 = nb1; i1 = ni1; b2v = nb2; i2 = ni2;                 \
    }

__global__ __launch_bounds__(256) void zero_kernel(int* __restrict__ p, int n) {
    const int i = blockIdx.x * 256 + threadIdx.x;
    if (i < n) p[i] = 0;
}

__device__ __forceinline__ int cell_of(float x, float y, float z) {
    int cx = (int)(x * (float)GRD); cx = cx < 0 ? 0 : (cx > GRD-1 ? GRD-1 : cx);
    int cy = (int)(y * (float)GRD); cy = cy < 0 ? 0 : (cy > GRD-1 ? GRD-1 : cy);
    int cz = (int)(z * (float)GRD); cz = cz < 0 ? 0 : (cz > GRD-1 ? GRD-1 : cz);
    return (cz << 6) | (cy << 3) | cx;
}

__global__ __launch_bounds__(256) void bin_count_kernel(
    const float* __restrict__ p2, int* __restrict__ counts) {
    const int i = blockIdx.x * 256 + threadIdx.x;      // 0..16383
    const float x = p2[i*3+0], y = p2[i*3+1], z = p2[i*3+2];
    const int cell = ((i >> 12) << 9) | cell_of(x, y, z);
    atomicAdd(&counts[cell], 1);
}

// exclusive scan of counts[2048] -> off[0..2048]
__global__ __launch_bounds__(256) void scan_kernel(
    const int* __restrict__ counts, int* __restrict__ off) {
    __shared__ int buf[2][256];
    const int t = threadIdx.x;
    int v[8]; int s = 0;
#pragma unroll
    for (int j = 0; j < 8; ++j) { const int tmp = counts[t*8+j]; v[j] = s; s += tmp; }
    buf[0][t] = s; __syncthreads();
    int src = 0;
    for (int d = 1; d < 256; d <<= 1) {
        int val = buf[src][t];
        if (t >= d) val += buf[src][t - d];
        buf[src ^ 1][t] = val; src ^= 1; __syncthreads();
    }
    const int incl = buf[src][t];
    const int base = incl - s;
#pragma unroll
    for (int j = 0; j < 8; ++j) off[t*8+j] = base + v[j];
    if (t == 255) off[2048] = incl;
}

__global__ __launch_bounds__(256) void bin_scatter_kernel(
    const float* __restrict__ p2, const int* __restrict__ off,
    int* __restrict__ cnt2, float4* __restrict__ binned) {
    const int i = blockIdx.x * 256 + threadIdx.x;      // 0..16383
    const float x = p2[i*3+0], y = p2[i*3+1], z = p2[i*3+2];
    const int cell = ((i >> 12) << 9) | cell_of(x, y, z);
    const int pos = off[cell] + atomicAdd(&cnt2[cell], 1);
    binned[pos] = make_float4(x, y, z, __int_as_float(i));
}

// 2 lanes per query; each scans half of every neighbor cell's point range,
// then one shfl-xor merge. Exact: accept only if 3rd-best dist is closer
// than any unscanned region; else masked brute-force rescan (rare).
__global__ __launch_bounds__(256) void knn_grid_kernel(
    const float* __restrict__ p1,      // [N1][3]
    const float4* __restrict__ binned, // [N2] (x,y,z,idx)
    const int* __restrict__ off,       // [2049]
    int*   __restrict__ idx_out,       // [3][N1]
    float* __restrict__ w_out)         // [3][N1]
{
    const int t   = blockIdx.x * 256 + threadIdx.x;
    const int fp  = t >> 1;
    const int sub = t & 1;
    const int bi  = fp >> 14;
    const int cbase = bi << 9;

    const float qx = p1[fp*3+0], qy = p1[fp*3+1], qz = p1[fp*3+2];
    int cx = (int)(qx * (float)GRD); cx = cx < 0 ? 0 : (cx > 7 ? 7 : cx);
    int cy = (int)(qy * (float)GRD); cy = cy < 0 ? 0 : (cy > 7 ? 7 : cy);
    int cz = (int)(qz * (float)GRD); cz = cz < 0 ? 0 : (cz > 7 ? 7 : cz);

    float b0 = 1e30f, b1 = 1e30f, b2v = 1e30f;
    int   i0 = 0,     i1 = 0,     i2 = 0;

    for (int dz = -1; dz <= 1; ++dz)
    for (int dy = -1; dy <= 1; ++dy)
    for (int dx = -1; dx <= 1; ++dx) {
        const int nx = cx + dx, ny = cy + dy, nz = cz + dz;
        if ((unsigned)nx > 7u || (unsigned)ny > 7u || (unsigned)nz > 7u) continue;
        const int c = cbase + (nz << 6) + (ny << 3) + nx;
        const int s = off[c], e = off[c + 1];
        for (int k = s + sub; k < e; k += 2) {
            const float4 c4 = binned[k];
            const float ddx = qx - c4.x, ddy = qy - c4.y, ddz = qz - c4.z;
            const float d2 = fmaf(ddx, ddx, fmaf(ddy, ddy, ddz * ddz));
            const int j = __float_as_int(c4.w);
            KNN_INSERT(d2, j)
        }
    }

    // merge the pair
    {
        const float c0v = __shfl_xor(b0, 1, 2);
        const float c1v = __shfl_xor(b1, 1, 2);
        const float c2v = __shfl_xor(b2v, 1, 2);
        const int   j0v = __shfl_xor(i0, 1, 2);
        const int   j1v = __shfl_xor(i1, 1, 2);
        const int   j2v = __shfl_xor(i2, 1, 2);
        KNN_INSERT(c0v, j0v)
        KNN_INSERT(c1v, j1v)
        KNN_INSERT(c2v, j2v)
    }

    // exactness check: nearest unscanned region (walls beyond [0,1] excluded)
    float dw = 1e30f;
    if (cx >= 2) dw = fminf(dw, qx - (float)(cx - 1) * HCELL);
    if (cx <= 5) dw = fminf(dw, (float)(cx + 2) * HCELL - qx);
    if (cy >= 2) dw = fminf(dw, qy - (float)(cy - 1) * HCELL);
    if (cy <= 5) dw = fminf(dw, (float)(cy + 2) * HCELL - qy);
    if (cz >= 2) dw = fminf(dw, qz - (float)(cz - 1) * HCELL);
    if (cz <= 5) dw = fminf(dw, (float)(cz + 2) * HCELL - qz);
    const bool done = b2v < dw * dw;

    if (!done) {   // rare; pair-uniform predicate
        b0 = b1 = b2v = 1e30f; i0 = i1 = i2 = 0;
        const int s = bi << 12, e = (bi + 1) << 12;
        for (int k = s + sub; k < e; k += 2) {
            const float4 c4 = binned[k];
            const float ddx = qx - c4.x, ddy = qy - c4.y, ddz = qz - c4.z;
            const float d2 = fmaf(ddx, ddx, fmaf(ddy, ddy, ddz * ddz));
            const int j = __float_as_int(c4.w);
            KNN_INSERT(d2, j)
        }
        const float c0v = __shfl_xor(b0, 1, 2);
        const float c1v = __shfl_xor(b1, 1, 2);
        const float c2v = __shfl_xor(b2v, 1, 2);
        const int   j0v = __shfl_xor(i0, 1, 2);
        const int   j1v = __shfl_xor(i1, 1, 2);
        const int   j2v = __shfl_xor(i2, 1, 2);
        KNN_INSERT(c0v, j0v)
        KNN_INSERT(c1v, j1v)
        KNN_INSERT(c2v, j2v)
    }

    if (sub == 0) {
        const float w0 = 1.f / (b0 + 1e-8f);
        const float w1 = 1.f / (b1 + 1e-8f);
        const float w2 = 1.f / (b2v + 1e-8f);
        const float inv = 1.f / (w0 + w1 + w2);
        idx_out[0*N1T + fp] = i0;
        idx_out[1*N1T + fp] = i1;
        idx_out[2*N1T + fp] = i2;
        w_out[0*N1T + fp] = w0 * inv;
        w_out[1*N1T + fp] = w1 * inv;
        w_out[2*N1T + fp] = w2 * inv;
    }
}

// ---------------------------------------------------------------------------
extern "C" void kernel_launch(void* const* d_in, const int* in_sizes, int n_in,
                              void* d_out, int out_size, void* d_ws, size_t ws_size,
                              hipStream_t stream) {
    const float* p1      = (const float*)d_in[0];
    const float* x1      = (const float*)d_in[1];
    const float* p2      = (const float*)d_in[3];
    const float* x2      = (const float*)d_in[4];
    const float* w1_feat = (const float*)d_in[6];
    const float* w1_dir  = (const float*)d_in[7];
    const float* w2_feat = (const float*)d_in[8];
    const float* w2_dir  = (const float*)d_in[9];
    float* out = (float*)d_out;

    // workspace layout (all chunks 16B-aligned)
    char* ws = (char*)d_ws;
    float*  y2t    = (float*)ws;                 ws += (size_t)N2T * CH * 4;   // 12.58 MB
    int*    idxs   = (int*)ws;                   ws += (size_t)3 * N1T * 4;    // 0.75 MB
    float*  wts    = (float*)ws;                 ws += (size_t)3 * N1T * 4;    // 0.75 MB
    int*    counts = (int*)ws;                   ws += 2048 * 4;
    int*    cnt2   = (int*)ws;                   ws += 2048 * 4;
    int*    off    = (int*)ws;                   ws += 2064 * 4;               // 2049 used
    float4* binned = (float4*)ws;                                              // 16384*16B

    // ---- kNN chain ----
    zero_kernel<<<16, 256, 0, stream>>>(counts, 4096);        // counts + cnt2 (contiguous)
    bin_count_kernel<<<N2T/256, 256, 0, stream>>>(p2, counts);
    scan_kernel<<<1, 256, 0, stream>>>(counts, off);
    bin_scatter_kernel<<<N2T/256, 256, 0, stream>>>(p2, off, cnt2, binned);
    knn_grid_kernel<<<(2*N1T)/256, 256, 0, stream>>>(p1, binned, off, idxs, wts);

    // y2 = VN(x2) -> point-major [N2][192]
    vn_kernel<128, false><<<N2T/64, 512, 0, stream>>>(
        x2, w2_feat, w2_dir, nullptr, nullptr, nullptr, y2t, N2T);
    // out = VN(x1) + interpolate(y2)   (fused epilogue)
    vn_kernel<64, true><<<N1T/64, 512, 0, stream>>>(
        x1, w1_feat, w1_dir, idxs, wts, y2t, out, N1T);
}